// Round 17
// baseline (657.597 us; speedup 1.0000x reference)
//
#include <hip/hip_runtime.h>

#define HID 256
#define NDRUG 20000
#define NDIS 20000
#define NE 400000
#define NEL 100000
#define NLAYERS 4

typedef float f32x4 __attribute__((ext_vector_type(4)));
typedef short s16x8 __attribute__((ext_vector_type(8)));
typedef unsigned short ushort_t;
typedef unsigned int uint_t;

// ---- bf16 helpers (round-to-nearest-even) ----
__device__ __forceinline__ ushort_t f2bf(float f) {
    uint_t u = __float_as_uint(f);
    u += 0x7fffu + ((u >> 16) & 1u);
    return (ushort_t)(u >> 16);
}
__device__ __forceinline__ float bf2f(uint_t h) {
    return __uint_as_float(h << 16);
}

// ---- async global->LDS, 16B per lane; LDS base must be wave-uniform ----
__device__ __forceinline__ void gl_lds16(const void* g, void* l) {
    __builtin_amdgcn_global_load_lds(
        (const __attribute__((address_space(1))) void*)g,
        (__attribute__((address_space(3))) void*)l, 16, 0, 0);
}

// ---- m204 bijective XCD-chunked swizzle ----
__device__ __forceinline__ int xcd_swz(int orig, int nwg) {
    int q = nwg >> 3, r = nwg & 7;
    int x = orig & 7, i = orig >> 3;
    int start = (x < r) ? x * (q + 1) : r * (q + 1) + (x - r) * q;
    return start + i;
}

// ---------------- mega prep: weight transpose+split (298) | init (20000) | count (2*nbE)
struct TP { const float* src[7]; ushort_t* th[7]; ushort_t* tl[7]; };
#define NBE 1563    // ceil(NE/256)
__global__ void k_prep(TP tp,
                       const int* __restrict__ drug_id, const float* __restrict__ drug_emb,
                       const float* __restrict__ dx, const float* __restrict__ Wlin,
                       const float* __restrict__ blin, const int* __restrict__ dis_id,
                       const float* __restrict__ dis_emb,
                       ushort_t* __restrict__ x_drug, ushort_t* __restrict__ x_dis,
                       const int* __restrict__ dst_mt, const int* __restrict__ dst_rev,
                       int* __restrict__ cnt_dis, int* __restrict__ cnt_drug)
{
    __shared__ float sm[64][65];
    __shared__ float xr[10];
    int bid = blockIdx.x;
    if (bid < 298) {
        const float* W; ushort_t *pth, *ptl; int K, N, n0, k0;
        if (bid < 256) {
            int fam = bid >> 6, l = (bid >> 4) & 3, t = bid & 15;
            W = tp.src[fam] + (size_t)l * 65536;
            pth = tp.th[fam] + (size_t)l * 65536;
            ptl = tp.tl[fam] + (size_t)l * 65536;
            K = 256; N = 256; n0 = (t & 3) * 64; k0 = (t >> 2) * 64;
        } else if (bid < 288) {
            int t = bid - 256; W = tp.src[4]; pth = tp.th[4]; ptl = tp.tl[4];
            K = 512; N = 256; n0 = (t & 3) * 64; k0 = (t >> 2) * 64;
        } else if (bid < 296) {
            int t = bid - 288; W = tp.src[5]; pth = tp.th[5]; ptl = tp.tl[5];
            K = 256; N = 128; n0 = (t & 1) * 64; k0 = (t >> 1) * 64;
        } else {
            int t = bid - 296; W = tp.src[6]; pth = tp.th[6]; ptl = tp.tl[6];
            K = 128; N = 64; n0 = 0; k0 = t * 64;
        }
        int tx = threadIdx.x & 63, ty = threadIdx.x >> 6;
        for (int r = ty; r < 64; r += 4) sm[r][tx] = W[(size_t)(k0 + r) * N + n0 + tx];
        __syncthreads();
        for (int r = ty; r < 64; r += 4) {
            float v = sm[tx][r];
            ushort_t h = f2bf(v);
            size_t o = (size_t)(n0 + r) * K + k0 + tx;
            pth[o] = h;
            ptl[o] = f2bf(v - bf2f(h));
        }
    } else if (bid < 20298) {
        int n = bid - 298; int h = threadIdx.x;
        size_t o = (size_t)n * HID + h;
        x_drug[o] = f2bf(drug_emb[(size_t)drug_id[n] * HID + h]);
        if (h < 10) xr[h] = dx[n * 10 + h];
        __syncthreads();
        float acc = blin[h] + dis_emb[(size_t)dis_id[n] * HID + h];
#pragma unroll
        for (int k = 0; k < 10; ++k) acc += xr[k] * Wlin[k * HID + h];
        x_dis[o] = f2bf(acc);
    } else {
        int idx = bid - 20298;
        bool second = idx >= NBE;
        const int* dst = second ? dst_rev : dst_mt;
        int* cnt = second ? cnt_drug : cnt_dis;
        int i = (second ? idx - NBE : idx) * 256 + threadIdx.x;
        if (i < NE) atomicAdd(&cnt[dst[i]], 1);
    }
}

// ---------------- fast hierarchical scan: 2 blocks x 1024 thr, seq-20 + block-scan
__global__ void k_scan2(const int* __restrict__ cntA, int* __restrict__ offA,
                        const int* __restrict__ cntB, int* __restrict__ offB, int n)
{
    const int* cnt = blockIdx.x ? cntB : cntA;
    int* off = blockIdx.x ? offB : offA;
    __shared__ int sm[1024];
    int tid = threadIdx.x;
    int base = tid * 20;
    int tsum = 0;
    for (int k = 0; k < 20; ++k) { int i = base + k; if (i < n) tsum += cnt[i]; }
    sm[tid] = tsum;
    __syncthreads();
    for (int o = 1; o < 1024; o <<= 1) {
        int t = (tid >= o) ? sm[tid - o] : 0;
        __syncthreads();
        sm[tid] += t;
        __syncthreads();
    }
    int run = sm[tid] - tsum;   // exclusive prefix
    if (tid == 0) off[0] = 0;
    for (int k = 0; k < 20; ++k) {
        int i = base + k;
        if (i < n) { run += cnt[i]; off[i + 1] = run; }
    }
}

// ---------------- fused CSR fill (both directions)
__global__ void k_fill2(const int* __restrict__ e_mt, const int* __restrict__ e_rev,
                        const int* __restrict__ off_dis, const int* __restrict__ off_drug,
                        int* __restrict__ cur_dis, int* __restrict__ cur_drug,
                        int* __restrict__ csr_mt, int* __restrict__ csr_rev)
{
    int b = blockIdx.x;
    bool second = b >= NBE;
    const int* src = second ? e_rev : e_mt;
    const int* dst = second ? (e_rev + NE) : (e_mt + NE);
    const int* off = second ? off_drug : off_dis;
    int* cur = second ? cur_drug : cur_dis;
    int* out = second ? csr_rev : csr_mt;
    int i = (second ? b - NBE : b) * 256 + threadIdx.x;
    if (i < NE) {
        int d = dst[i];
        int p = atomicAdd(&cur[d], 1);
        out[off[d] + p] = src[i];
    }
}

// ---------------- GEMM job (round-12/14 verified A-share alternating-B pipeline)
struct GJob {
    const ushort_t* A[2];
    const ushort_t* Bh[2];
    const ushort_t* Bl[2];
    int astride, wstride;
    const float* bias;
    int M, N, relu;
    ushort_t* C;
};
// ---------------- agg job (round-13 verified uint4 mean-agg, one direction)
struct AJob { const uint_t* x; const int* off; const int* csr; uint_t* out; };

// ---------------- fused layer dispatch: blocks [0,gemmBlocks) = one side's GEMM
// (RACE-FREE 1-barrier counted-vmcnt schedule, verbatim round-14 math);
// blocks [gemmBlocks, gemmBlocks+10000) = one side's mean-agg (2 dst/block).
// GEMM waves feed MFMA/LDS while agg waves saturate memory (overlap).
__global__ __launch_bounds__(256, 4) void k_lag(GJob j, int gemmBlocks, AJob aj)
{
    // GEMM: A slots [0,8192) ushorts (2 x 4096), B slots [8192,20480) (3 x 4096)
    // agg:  red = first 2*32*8 floats
    __shared__ __align__(16) ushort_t sm[20480];

    const int tid = threadIdx.x;
    const int bid = blockIdx.x;

    if (bid < gemmBlocks) {
        const int lane = tid & 63;
        const int wv = tid >> 6;
        const int t = xcd_swz(bid, gemmBlocks);
        const int bm = (t >> 1) * 128;
        const int bn = (t & 1) * 128;

        const int q = tid >> 2;                                   // 0..63
        const int skz = (((tid & 3) ^ ((tid >> 3) & 3)) << 3);    // chunk-XOR swizzle

        int tr0 = bm + q;       if (tr0 > j.M - 1) tr0 = j.M - 1;
        int tr1 = bm + 64 + q;  if (tr1 > j.M - 1) tr1 = j.M - 1;
        const size_t aoff0 = (size_t)tr0 * j.astride + skz;
        const size_t aoff1 = (size_t)tr1 * j.astride + skz;
        const size_t boff = (size_t)(bn + q) * j.wstride + skz;
        const size_t ws64 = (size_t)64 * j.wstride;

        auto STAGE_A = [&](int u, int slot) {       // u in [0,16): a = u>>3, ks = u&7
            const int a = u >> 3, ks = u & 7;
            const ushort_t* Ap = j.A[a] + (size_t)ks * 32;
            gl_lds16(Ap + aoff0, &sm[slot * 4096 + wv * 512]);
            gl_lds16(Ap + aoff1, &sm[slot * 4096 + 2048 + wv * 512]);
        };
        auto STAGE_B = [&](int s2, int slot) {
            const int u = s2 >> 1, a = u >> 3, ks = u & 7, h = s2 & 1;
            const ushort_t* Bp = (h ? j.Bl[a] : j.Bh[a]) + boff + (size_t)ks * 32;
            gl_lds16(Bp,        &sm[8192 + slot * 4096 + wv * 512]);
            gl_lds16(Bp + ws64, &sm[8192 + slot * 4096 + 2048 + wv * 512]);
        };

        f32x4 acc[4][4] = {};
        s16x8 a_frag[4];
        const int arow = lane & 15;
        const int k8s = ((lane >> 4) * 8) ^ (((arow >> 1) & 3) << 3);
        const int wrA = (wv >> 1) * 64;
        const int wrB = (wv & 1) * 64;

        constexpr int NS = 32;
        STAGE_A(0, 0); STAGE_B(0, 0);     // 4 loads (step 0)
        STAGE_B(1, 1);                    // 2 loads (step 1)
        asm volatile("s_waitcnt vmcnt(2)" ::: "memory");
        __builtin_amdgcn_sched_barrier(0);
        __builtin_amdgcn_s_barrier();

#pragma unroll
        for (int s = 0; s < NS; ++s) {
            const int bslot = s % 3;
            if (s + 2 < NS) {
                if (((s + 2) & 1) == 0) STAGE_A((s + 2) >> 1, ((s + 2) >> 1) & 1);
                STAGE_B(s + 2, (s + 2) % 3);
            }
            if ((s & 1) == 0) {
                const int aslot = (s >> 1) & 1;
#pragma unroll
                for (int m = 0; m < 4; ++m)
                    a_frag[m] = *(const s16x8*)&sm[aslot * 4096 + (wrA + m * 16 + arow) * 32 + k8s];
            }
            __builtin_amdgcn_s_setprio(1);
#pragma unroll
            for (int n = 0; n < 4; ++n) {
                s16x8 b = *(const s16x8*)&sm[8192 + bslot * 4096 + (wrB + n * 16 + arow) * 32 + k8s];
#pragma unroll
                for (int m = 0; m < 4; ++m)
                    acc[m][n] = __builtin_amdgcn_mfma_f32_16x16x32_bf16(a_frag[m], b, acc[m][n], 0, 0, 0);
            }
            __builtin_amdgcn_s_setprio(0);
            if (s + 2 < NS) {
                if (((s + 2) & 1) == 0) asm volatile("s_waitcnt vmcnt(4)" ::: "memory");
                else                    asm volatile("s_waitcnt vmcnt(2)" ::: "memory");
            } else {
                asm volatile("s_waitcnt vmcnt(0)" ::: "memory");
            }
            __builtin_amdgcn_sched_barrier(0);
            __builtin_amdgcn_s_barrier();
        }

        const int colC = lane & 15;
        const int rb = (lane >> 4) * 4;
#pragma unroll
        for (int m = 0; m < 4; ++m) {
#pragma unroll
            for (int jj = 0; jj < 4; ++jj) {
                const int r = bm + wrA + m * 16 + rb + jj;
                if (r < j.M) {
#pragma unroll
                    for (int n = 0; n < 4; ++n) {
                        const int c = bn + wrB + n * 16 + colC;
                        if (c < j.N) {
                            float v = acc[m][n][jj] + j.bias[c];
                            if (j.relu) v = fmaxf(v, 0.f);
                            j.C[(size_t)r * j.N + c] = f2bf(v);
                        }
                    }
                }
            }
        }
    } else {
        // ---- mean-agg: 2 dst nodes per 256-thread block ----
        const int grp = tid >> 7;          // 0,1: which dst of the pair
        const int sub = tid & 127;
        const int d = (bid - gemmBlocks) * 2 + grp;
        const int slot = sub >> 5;         // 0..3: edge slot
        const int lr = sub & 31;           // lane within row (16B each)
        int s = aj.off[d], e = aj.off[d + 1];
        float a[8] = {};
        auto ACC = [&](uint4 v) {
            a[0] += bf2f(v.x & 0xffffu); a[1] += bf2f(v.x >> 16);
            a[2] += bf2f(v.y & 0xffffu); a[3] += bf2f(v.y >> 16);
            a[4] += bf2f(v.z & 0xffffu); a[5] += bf2f(v.z >> 16);
            a[6] += bf2f(v.w & 0xffffu); a[7] += bf2f(v.w >> 16);
        };
        int i = s;
        for (; i + 8 <= e; i += 8) {
            int i0 = aj.csr[i + slot], i1 = aj.csr[i + 4 + slot];
            uint4 v0 = *(const uint4*)&aj.x[(size_t)i0 * 128 + lr * 4];
            uint4 v1 = *(const uint4*)&aj.x[(size_t)i1 * 128 + lr * 4];
            ACC(v0); ACC(v1);
        }
        for (; i + 4 <= e; i += 4) {
            int i0 = aj.csr[i + slot];
            uint4 v0 = *(const uint4*)&aj.x[(size_t)i0 * 128 + lr * 4];
            ACC(v0);
        }
        int rem = e - i;
        if (slot < rem) {
            int i0 = aj.csr[i + slot];
            uint4 v0 = *(const uint4*)&aj.x[(size_t)i0 * 128 + lr * 4];
            ACC(v0);
        }
#pragma unroll
        for (int jx = 0; jx < 8; ++jx) a[jx] += __shfl_xor(a[jx], 32);
        float* red = (float*)sm;            // [2][32][8]
        if (sub >= 64 && sub < 96) {
#pragma unroll
            for (int jx = 0; jx < 8; ++jx) red[(grp * 32 + lr) * 8 + jx] = a[jx];
        }
        __syncthreads();
        if (sub < 32) {
            float inv = 1.f / fmaxf((float)(e - s), 1.f);
            const float* rd = &red[(grp * 32 + lr) * 8];
            uint4 o;
            float r0, r1;
            r0 = (a[0] + rd[0]) * inv; r1 = (a[1] + rd[1]) * inv;
            o.x = (uint_t)f2bf(r0) | ((uint_t)f2bf(r1) << 16);
            r0 = (a[2] + rd[2]) * inv; r1 = (a[3] + rd[3]) * inv;
            o.y = (uint_t)f2bf(r0) | ((uint_t)f2bf(r1) << 16);
            r0 = (a[4] + rd[4]) * inv; r1 = (a[5] + rd[5]) * inv;
            o.z = (uint_t)f2bf(r0) | ((uint_t)f2bf(r1) << 16);
            r0 = (a[6] + rd[6]) * inv; r1 = (a[7] + rd[7]) * inv;
            o.w = (uint_t)f2bf(r0) | ((uint_t)f2bf(r1) << 16);
            *(uint4*)&aj.out[(size_t)d * 128 + lr * 4] = o;
        }
    }
}

// ---------------- fully fused classifier (round-12/14 verified version)
__global__ __launch_bounds__(256, 2) void k_cls(
    const ushort_t* __restrict__ xg, const ushort_t* __restrict__ xd,
    const int* __restrict__ elbl,
    const ushort_t* __restrict__ w1h, const ushort_t* __restrict__ w1l,
    const ushort_t* __restrict__ w2h, const ushort_t* __restrict__ w2l,
    const ushort_t* __restrict__ w3h, const ushort_t* __restrict__ w3l,
    const float* __restrict__ b1, const float* __restrict__ b2,
    const float* __restrict__ b3, const float* __restrict__ w4,
    const float* __restrict__ b4, float* __restrict__ out, int M)
{
    // staging: A = [0,4096) (2 slots x 2048), B = [4096,28672) (3 slots x 8192)
    // post-fc1 reuse: e1 = [0,16384), e2 = [16384,24576), part = [24576,25088)
    __shared__ __align__(16) ushort_t sm[28672];

    const int tid = threadIdx.x;
    const int lane = tid & 63;
    const int wv = tid >> 6;
    const int bm = blockIdx.x * 64;
    const int arow = lane & 15;
    const int kq = lane >> 4;          // 0..3
    const int rb = kq * 4;
    const int colC = arow;

    const int q = tid >> 2;                                   // 0..63
    const int skz = (((tid & 3) ^ ((tid >> 3) & 3)) << 3);    // chunk-XOR swizzle

    int r0 = bm + q; if (r0 > M - 1) r0 = M - 1;
    const size_t aoff[2] = { (size_t)elbl[r0] * 256 + skz,
                             (size_t)elbl[NEL + r0] * 256 + skz };
    const ushort_t* xsrc[2] = { xg, xd };
    const size_t bq = (size_t)q * 512 + skz;

    auto STAGE_A = [&](int u, int slot) {           // 1 load; u: pass u>>3, k-chunk u&7
        const int p = u >> 3, ks = u & 7;
        gl_lds16(xsrc[p] + aoff[p] + ks * 32, &sm[slot * 2048 + wv * 512]);
    };
    auto STAGE_B = [&](int s2, int slot) {          // 4 loads: 256-row B tile
        const int u = s2 >> 1, p = u >> 3, ks = u & 7, h = s2 & 1;
        const ushort_t* W = (h ? w1l : w1h) + (size_t)p * 256 + (size_t)ks * 32 + bq;
        ushort_t* db = &sm[4096 + slot * 8192 + wv * 512];
#pragma unroll
        for (int i = 0; i < 4; ++i)
            gl_lds16(W + (size_t)i * 64 * 512, db + i * 2048);
    };

    f32x4 acc1[4][4] = {};
    s16x8 af[4];
    const int k8s = (kq * 8) ^ (((arow >> 1) & 3) << 3);

    STAGE_A(0, 0); STAGE_B(0, 0);     // 5 loads (step 0)
    STAGE_B(1, 1);                    // 4 loads (step 1)
    asm volatile("s_waitcnt vmcnt(4)" ::: "memory");   // drain step 0
    __builtin_amdgcn_sched_barrier(0);
    __builtin_amdgcn_s_barrier();

#pragma unroll
    for (int s = 0; s < 32; ++s) {
        const int bslot = s % 3;
        if (s + 2 < 32) {
            if (((s + 2) & 1) == 0) STAGE_A((s + 2) >> 1, ((s + 2) >> 1) & 1);
            STAGE_B(s + 2, (s + 2) % 3);
        }
        if ((s & 1) == 0) {
            const int aslot = (s >> 1) & 1;
#pragma unroll
            for (int m = 0; m < 4; ++m)
                af[m] = *(const s16x8*)&sm[aslot * 2048 + (m * 16 + arow) * 32 + k8s];
        }
        __builtin_amdgcn_s_setprio(1);
#pragma unroll
        for (int n = 0; n < 4; ++n) {
            s16x8 b = *(const s16x8*)&sm[4096 + bslot * 8192 + (wv * 64 + n * 16 + arow) * 32 + k8s];
#pragma unroll
            for (int m = 0; m < 4; ++m)
                acc1[m][n] = __builtin_amdgcn_mfma_f32_16x16x32_bf16(af[m], b, acc1[m][n], 0, 0, 0);
        }
        __builtin_amdgcn_s_setprio(0);
        if (s + 2 < 32) {
            if (((s + 2) & 1) == 0) asm volatile("s_waitcnt vmcnt(5)" ::: "memory");
            else                    asm volatile("s_waitcnt vmcnt(4)" ::: "memory");
        } else {
            asm volatile("s_waitcnt vmcnt(0)" ::: "memory");
        }
        __builtin_amdgcn_sched_barrier(0);
        __builtin_amdgcn_s_barrier();
    }

    // e1 -> LDS [64][256] bf16, chunk-XOR swizzled (chunk ^= row&7)
#pragma unroll
    for (int m = 0; m < 4; ++m)
#pragma unroll
        for (int n = 0; n < 4; ++n)
#pragma unroll
            for (int jj = 0; jj < 4; ++jj) {
                int row = m * 16 + rb + jj;
                int col = wv * 64 + n * 16 + colC;
                float v = acc1[m][n][jj] + b1[col];
                v = fmaxf(v, 0.f);
                int c = col >> 3;
                sm[row * 256 + (((c ^ (row & 7)) << 3) | (col & 7))] = f2bf(v);
            }
    __syncthreads();

    // ---- phase 2: fc2 (K=256, N=128). A from e1 LDS; B direct global ----
    f32x4 acc2[4][2] = {};
#pragma unroll
    for (int k = 0; k < 8; ++k) {
        s16x8 a2[4];
#pragma unroll
        for (int m = 0; m < 4; ++m) {
            int row = m * 16 + arow;
            int c = k * 4 + kq;
            a2[m] = *(const s16x8*)&sm[row * 256 + ((c ^ (row & 7)) << 3)];
        }
#pragma unroll
        for (int nt = 0; nt < 2; ++nt) {
            size_t bo = (size_t)(wv * 32 + nt * 16 + arow) * 256 + k * 32 + kq * 8;
            s16x8 bh = *(const s16x8*)(w2h + bo);
            s16x8 bl = *(const s16x8*)(w2l + bo);
#pragma unroll
            for (int m = 0; m < 4; ++m) {
                acc2[m][nt] = __builtin_amdgcn_mfma_f32_16x16x32_bf16(a2[m], bh, acc2[m][nt], 0, 0, 0);
                acc2[m][nt] = __builtin_amdgcn_mfma_f32_16x16x32_bf16(a2[m], bl, acc2[m][nt], 0, 0, 0);
            }
        }
    }
    // e2 -> LDS [64][128] bf16 swizzled (disjoint region from e1)
#pragma unroll
    for (int m = 0; m < 4; ++m)
#pragma unroll
        for (int nt = 0; nt < 2; ++nt)
#pragma unroll
            for (int jj = 0; jj < 4; ++jj) {
                int row = m * 16 + rb + jj;
                int col = wv * 32 + nt * 16 + colC;
                float v = acc2[m][nt][jj] + b2[col];
                v = fmaxf(v, 0.f);
                int c = col >> 3;
                sm[16384 + row * 128 + (((c ^ (row & 7)) << 3) | (col & 7))] = f2bf(v);
            }
    __syncthreads();

    // ---- phase 3: fc3 (K=128, N=64). Wave wv owns cols wv*16..+15 ----
    f32x4 acc3[4] = {};
#pragma unroll
    for (int k = 0; k < 4; ++k) {
        s16x8 a3[4];
#pragma unroll
        for (int m = 0; m < 4; ++m) {
            int row = m * 16 + arow;
            int c = k * 4 + kq;
            a3[m] = *(const s16x8*)&sm[16384 + row * 128 + ((c ^ (row & 7)) << 3)];
        }
        size_t bo = (size_t)(wv * 16 + arow) * 128 + k * 32 + kq * 8;
        s16x8 bh = *(const s16x8*)(w3h + bo);
        s16x8 bl = *(const s16x8*)(w3l + bo);
#pragma unroll
        for (int m = 0; m < 4; ++m) {
            acc3[m] = __builtin_amdgcn_mfma_f32_16x16x32_bf16(a3[m], bh, acc3[m], 0, 0, 0);
            acc3[m] = __builtin_amdgcn_mfma_f32_16x16x32_bf16(a3[m], bl, acc3[m], 0, 0, 0);
        }
    }

    // ---- phase 4: fc4 dot. 16-lane shfl reduce, then cross-wave LDS sum ----
    float* part = (float*)&sm[24576];   // [4][64]
#pragma unroll
    for (int m = 0; m < 4; ++m)
#pragma unroll
        for (int jj = 0; jj < 4; ++jj) {
            int row = m * 16 + rb + jj;
            int col = wv * 16 + colC;
            float e = acc3[m][jj] + b3[col];
            e = fmaxf(e, 0.f);
            float v = e * w4[col];
#pragma unroll
            for (int o = 1; o < 16; o <<= 1) v += __shfl_xor(v, o);
            if (colC == 0) part[wv * 64 + row] = v;
        }
    __syncthreads();
    if (tid < 64) {
        int rr = bm + tid;
        if (rr < M)
            out[rr] = part[tid] + part[64 + tid] + part[128 + tid] + part[192 + tid] + b4[0];
    }
}

extern "C" void kernel_launch(void* const* d_in, const int* in_sizes, int n_in,
                              void* d_out, int out_size, void* d_ws, size_t ws_size,
                              hipStream_t stream)
{
    const int*   drug_id   = (const int*)d_in[0];
    const float* disease_x = (const float*)d_in[1];
    const int*   dis_id    = (const int*)d_in[2];
    const int*   e_mt      = (const int*)d_in[3];
    const int*   e_rev     = (const int*)d_in[4];
    const int*   e_lbl     = (const int*)d_in[5];
    const float* drug_emb  = (const float*)d_in[6];
    const float* dis_emb   = (const float*)d_in[7];
    const float* lin_w     = (const float*)d_in[8];
    const float* lin_b     = (const float*)d_in[9];
    const float* Wl_mt     = (const float*)d_in[10];
    const float* bl_mt     = (const float*)d_in[11];
    const float* Wr_mt     = (const float*)d_in[12];
    const float* Wl_rev    = (const float*)d_in[13];
    const float* bl_rev    = (const float*)d_in[14];
    const float* Wr_rev    = (const float*)d_in[15];
    const float* fc1_w = (const float*)d_in[16]; const float* fc1_b = (const float*)d_in[17];
    const float* fc2_w = (const float*)d_in[18]; const float* fc2_b = (const float*)d_in[19];
    const float* fc3_w = (const float*)d_in[20]; const float* fc3_b = (const float*)d_in[21];
    const float* fc4_w = (const float*)d_in[22]; const float* fc4_b = (const float*)d_in[23];
    float* out = (float*)d_out;

    // ---- workspace layout (~95 MB) ----
    char* base = (char*)d_ws;
    size_t o = 0;
    auto alloc = [&](size_t bytes) { char* r = base + o; o += (bytes + 255) & ~(size_t)255; return r; };
    const size_t XB = (size_t)20000 * 256 * 2;   // one bf16 activation plane

    ushort_t* x_dis   = (ushort_t*)alloc(XB);
    ushort_t* x_drug  = (ushort_t*)alloc(XB);
    ushort_t* y_dis   = (ushort_t*)alloc(XB);
    ushort_t* y_drug  = (ushort_t*)alloc(XB);
    ushort_t* agd0    = (ushort_t*)alloc(XB);    // agg_dis double-buffer
    ushort_t* agd1    = (ushort_t*)alloc(XB);
    ushort_t* agr0    = (ushort_t*)alloc(XB);    // agg_drug double-buffer
    ushort_t* agr1    = (ushort_t*)alloc(XB);
    const size_t WB = (size_t)4 * 256 * 256 * 2;
    ushort_t* wlmt_h  = (ushort_t*)alloc(WB); ushort_t* wlmt_l  = (ushort_t*)alloc(WB);
    ushort_t* wrmt_h  = (ushort_t*)alloc(WB); ushort_t* wrmt_l  = (ushort_t*)alloc(WB);
    ushort_t* wlrev_h = (ushort_t*)alloc(WB); ushort_t* wlrev_l = (ushort_t*)alloc(WB);
    ushort_t* wrrev_h = (ushort_t*)alloc(WB); ushort_t* wrrev_l = (ushort_t*)alloc(WB);
    ushort_t* fc1t_h  = (ushort_t*)alloc(512 * 256 * 2); ushort_t* fc1t_l = (ushort_t*)alloc(512 * 256 * 2);
    ushort_t* fc2t_h  = (ushort_t*)alloc(256 * 128 * 2); ushort_t* fc2t_l = (ushort_t*)alloc(256 * 128 * 2);
    ushort_t* fc3t_h  = (ushort_t*)alloc(128 * 64 * 2);  ushort_t* fc3t_l = (ushort_t*)alloc(128 * 64 * 2);
    int* cnts     = (int*)alloc(80000 * 4);
    int* cnt_dis  = cnts;
    int* cnt_drug = cnts + 20000;
    int* cur_dis  = cnts + 40000;
    int* cur_drug = cnts + 60000;
    int* off_dis  = (int*)alloc(20004 * 4);
    int* off_drug = (int*)alloc(20004 * 4);
    int* csr_mt   = (int*)alloc(400000 * 4);
    int* csr_rev  = (int*)alloc(400000 * 4);

    hipMemsetAsync(cnts, 0, 80000 * sizeof(int), stream);

    TP tp;
    tp.src[0] = Wl_mt;  tp.th[0] = wlmt_h;  tp.tl[0] = wlmt_l;
    tp.src[1] = Wr_mt;  tp.th[1] = wrmt_h;  tp.tl[1] = wrmt_l;
    tp.src[2] = Wl_rev; tp.th[2] = wlrev_h; tp.tl[2] = wlrev_l;
    tp.src[3] = Wr_rev; tp.th[3] = wrrev_h; tp.tl[3] = wrrev_l;
    tp.src[4] = fc1_w;  tp.th[4] = fc1t_h;  tp.tl[4] = fc1t_l;
    tp.src[5] = fc2_w;  tp.th[5] = fc2t_h;  tp.tl[5] = fc2t_l;
    tp.src[6] = fc3_w;  tp.th[6] = fc3t_h;  tp.tl[6] = fc3t_l;

    // mega prep: trans (298) | init (20000) | count (2*NBE)
    k_prep<<<298 + 20000 + 2 * NBE, 256, 0, stream>>>(
        tp, drug_id, drug_emb, disease_x, lin_w, lin_b, dis_id, dis_emb,
        x_drug, x_dis, e_mt + NE, e_rev + NE, cnt_dis, cnt_drug);
    k_scan2<<<2, 1024, 0, stream>>>(cnt_dis, off_dis, cnt_drug, off_drug, 20000);
    k_fill2<<<2 * NBE, 256, 0, stream>>>(e_mt, e_rev, off_dis, off_drug,
                                         cur_dis, cur_drug, csr_mt, csr_rev);

    // ---- skewed side-split layer pipeline ----
    ushort_t* XD[2] = { x_dis, y_dis };
    ushort_t* XG[2] = { x_drug, y_drug };
    ushort_t* AGD[2] = { agd0, agd1 };
    ushort_t* AGR[2] = { agr0, agr1 };
    const int GB = 157 * 2;     // GEMM blocks per side (128x128 tiles, nTiles=2)
    const int AB = 10000;       // agg blocks (2 dst each)

    auto mkGemD = [&](int l) {
        size_t wo = (size_t)l * 65536;
        GJob j = { { AGD[l & 1], XD[l & 1] },
                   { wlmt_h + wo, wrmt_h + wo }, { wlmt_l + wo, wrmt_l + wo },
                   256, 256, bl_mt + l * HID, NDIS, 256, (l < 3) ? 1 : 0,
                   XD[(l + 1) & 1] };
        return j;
    };
    auto mkGemG = [&](int l) {
        size_t wo = (size_t)l * 65536;
        GJob j = { { AGR[l & 1], XG[l & 1] },
                   { wlrev_h + wo, wrrev_h + wo }, { wlrev_l + wo, wrrev_l + wo },
                   256, 256, bl_rev + l * HID, NDRUG, 256, (l < 3) ? 1 : 0,
                   XG[(l + 1) & 1] };
        return j;
    };
    auto mkAggD = [&](int l) {
        AJob a = { (const uint_t*)XG[l & 1], off_dis, csr_mt, (uint_t*)AGD[l & 1] };
        return a;
    };
    auto mkAggG = [&](int l) {
        AJob a = { (const uint_t*)XD[l & 1], off_drug, csr_rev, (uint_t*)AGR[l & 1] };
        return a;
    };
    GJob gd = {};   // dummy (never executed when gemmBlocks==0)
    AJob ad = {};

    // D0: aggD(0)
    k_lag<<<AB, 256, 0, stream>>>(gd, 0, mkAggD(0));
    // D1: GemD(0) || aggG(0)
    k_lag<<<GB + AB, 256, 0, stream>>>(mkGemD(0), GB, mkAggG(0));
    // D2: GemG(0) || aggG(1)
    k_lag<<<GB + AB, 256, 0, stream>>>(mkGemG(0), GB, mkAggG(1));
    // D3: GemG(1) || aggD(1)
    k_lag<<<GB + AB, 256, 0, stream>>>(mkGemG(1), GB, mkAggD(1));
    // D4: GemD(1) || aggD(2)
    k_lag<<<GB + AB, 256, 0, stream>>>(mkGemD(1), GB, mkAggD(2));
    // D5: GemD(2) || aggG(2)
    k_lag<<<GB + AB, 256, 0, stream>>>(mkGemD(2), GB, mkAggG(2));
    // D6: GemG(2) || aggG(3)
    k_lag<<<GB + AB, 256, 0, stream>>>(mkGemG(2), GB, mkAggG(3));
    // D7: GemG(3) || aggD(3)
    k_lag<<<GB + AB, 256, 0, stream>>>(mkGemG(3), GB, mkAggD(3));
    // D8: GemD(3)
    k_lag<<<GB, 256, 0, stream>>>(mkGemD(3), GB, ad);

    // final planes: xg = XG[0] = x_drug, xd = XD[0] = x_dis
    k_cls<<<(NEL + 63) / 64, 256, 0, stream>>>(
        x_drug, x_dis, e_lbl, fc1t_h, fc1t_l, fc2t_h, fc2t_l, fc3t_h, fc3t_l,
        fc1_b, fc2_b, fc3_b, fc4_w, fc4_b, out, NEL);
}

// Round 18
// 568.886 us; speedup vs baseline: 1.1559x; 1.1559x over previous
//
#include <hip/hip_runtime.h>

#define HID 256
#define NDRUG 20000
#define NDIS 20000
#define NE 400000
#define NEL 100000
#define NLAYERS 4

typedef float f32x4 __attribute__((ext_vector_type(4)));
typedef short s16x8 __attribute__((ext_vector_type(8)));
typedef unsigned short ushort_t;
typedef unsigned int uint_t;

// ---- bf16 helpers (round-to-nearest-even) ----
__device__ __forceinline__ ushort_t f2bf(float f) {
    uint_t u = __float_as_uint(f);
    u += 0x7fffu + ((u >> 16) & 1u);
    return (ushort_t)(u >> 16);
}
__device__ __forceinline__ float bf2f(uint_t h) {
    return __uint_as_float(h << 16);
}

// ---- async global->LDS, 16B per lane; LDS base must be wave-uniform ----
__device__ __forceinline__ void gl_lds16(const void* g, void* l) {
    __builtin_amdgcn_global_load_lds(
        (const __attribute__((address_space(1))) void*)g,
        (__attribute__((address_space(3))) void*)l, 16, 0, 0);
}

// ---- m204 bijective XCD-chunked swizzle ----
__device__ __forceinline__ int xcd_swz(int orig, int nwg) {
    int q = nwg >> 3, r = nwg & 7;
    int x = orig & 7, i = orig >> 3;
    int start = (x < r) ? x * (q + 1) : r * (q + 1) + (x - r) * q;
    return start + i;
}

// ---------------- mega prep: weight transpose+split (298) | init (20000) | count (2*nbE)
struct TP { const float* src[7]; ushort_t* th[7]; ushort_t* tl[7]; };
#define NBE 1563    // ceil(NE/256)
__global__ void k_prep(TP tp,
                       const int* __restrict__ drug_id, const float* __restrict__ drug_emb,
                       const float* __restrict__ dx, const float* __restrict__ Wlin,
                       const float* __restrict__ blin, const int* __restrict__ dis_id,
                       const float* __restrict__ dis_emb,
                       ushort_t* __restrict__ x_drug, ushort_t* __restrict__ x_dis,
                       const int* __restrict__ dst_mt, const int* __restrict__ dst_rev,
                       int* __restrict__ cnt_dis, int* __restrict__ cnt_drug)
{
    __shared__ float sm[64][65];
    __shared__ float xr[10];
    int bid = blockIdx.x;
    if (bid < 298) {
        const float* W; ushort_t *pth, *ptl; int K, N, n0, k0;
        if (bid < 256) {
            int fam = bid >> 6, l = (bid >> 4) & 3, t = bid & 15;
            W = tp.src[fam] + (size_t)l * 65536;
            pth = tp.th[fam] + (size_t)l * 65536;
            ptl = tp.tl[fam] + (size_t)l * 65536;
            K = 256; N = 256; n0 = (t & 3) * 64; k0 = (t >> 2) * 64;
        } else if (bid < 288) {
            int t = bid - 256; W = tp.src[4]; pth = tp.th[4]; ptl = tp.tl[4];
            K = 512; N = 256; n0 = (t & 3) * 64; k0 = (t >> 2) * 64;
        } else if (bid < 296) {
            int t = bid - 288; W = tp.src[5]; pth = tp.th[5]; ptl = tp.tl[5];
            K = 256; N = 128; n0 = (t & 1) * 64; k0 = (t >> 1) * 64;
        } else {
            int t = bid - 296; W = tp.src[6]; pth = tp.th[6]; ptl = tp.tl[6];
            K = 128; N = 64; n0 = 0; k0 = t * 64;
        }
        int tx = threadIdx.x & 63, ty = threadIdx.x >> 6;
        for (int r = ty; r < 64; r += 4) sm[r][tx] = W[(size_t)(k0 + r) * N + n0 + tx];
        __syncthreads();
        for (int r = ty; r < 64; r += 4) {
            float v = sm[tx][r];
            ushort_t h = f2bf(v);
            size_t o = (size_t)(n0 + r) * K + k0 + tx;
            pth[o] = h;
            ptl[o] = f2bf(v - bf2f(h));
        }
    } else if (bid < 20298) {
        int n = bid - 298; int h = threadIdx.x;
        size_t o = (size_t)n * HID + h;
        x_drug[o] = f2bf(drug_emb[(size_t)drug_id[n] * HID + h]);
        if (h < 10) xr[h] = dx[n * 10 + h];
        __syncthreads();
        float acc = blin[h] + dis_emb[(size_t)dis_id[n] * HID + h];
#pragma unroll
        for (int k = 0; k < 10; ++k) acc += xr[k] * Wlin[k * HID + h];
        x_dis[o] = f2bf(acc);
    } else {
        int idx = bid - 20298;
        bool second = idx >= NBE;
        const int* dst = second ? dst_rev : dst_mt;
        int* cnt = second ? cnt_drug : cnt_dis;
        int i = (second ? idx - NBE : idx) * 256 + threadIdx.x;
        if (i < NE) atomicAdd(&cnt[dst[i]], 1);
    }
}

// ---------------- fast hierarchical scan: 2 blocks x 1024 thr, seq-20 + block-scan
__global__ void k_scan2(const int* __restrict__ cntA, int* __restrict__ offA,
                        const int* __restrict__ cntB, int* __restrict__ offB, int n)
{
    const int* cnt = blockIdx.x ? cntB : cntA;
    int* off = blockIdx.x ? offB : offA;
    __shared__ int sm[1024];
    int tid = threadIdx.x;
    int base = tid * 20;
    int tsum = 0;
    for (int k = 0; k < 20; ++k) { int i = base + k; if (i < n) tsum += cnt[i]; }
    sm[tid] = tsum;
    __syncthreads();
    for (int o = 1; o < 1024; o <<= 1) {
        int t = (tid >= o) ? sm[tid - o] : 0;
        __syncthreads();
        sm[tid] += t;
        __syncthreads();
    }
    int run = sm[tid] - tsum;   // exclusive prefix
    if (tid == 0) off[0] = 0;
    for (int k = 0; k < 20; ++k) {
        int i = base + k;
        if (i < n) { run += cnt[i]; off[i + 1] = run; }
    }
}

// ---------------- fused CSR fill (both directions)
__global__ void k_fill2(const int* __restrict__ e_mt, const int* __restrict__ e_rev,
                        const int* __restrict__ off_dis, const int* __restrict__ off_drug,
                        int* __restrict__ cur_dis, int* __restrict__ cur_drug,
                        int* __restrict__ csr_mt, int* __restrict__ csr_rev)
{
    int b = blockIdx.x;
    bool second = b >= NBE;
    const int* src = second ? e_rev : e_mt;
    const int* dst = second ? (e_rev + NE) : (e_mt + NE);
    const int* off = second ? off_drug : off_dis;
    int* cur = second ? cur_drug : cur_dis;
    int* out = second ? csr_rev : csr_mt;
    int i = (second ? b - NBE : b) * 256 + threadIdx.x;
    if (i < NE) {
        int d = dst[i];
        int p = atomicAdd(&cur[d], 1);
        out[off[d] + p] = src[i];
    }
}

// ---------------- fused dual mean-aggregation, uint4 lanes (32 lanes/row, 4 edges/group)
__global__ void k_agg2(const uint_t* __restrict__ x0, const int* __restrict__ off0,
                       const int* __restrict__ csr0, uint_t* __restrict__ o0,
                       const uint_t* __restrict__ x1, const int* __restrict__ off1,
                       const int* __restrict__ csr1, uint_t* __restrict__ o1)
{
    __shared__ float red[32][8];
    int d = blockIdx.x;
    const uint_t* x; const int* off; const int* csr; uint_t* ou;
    if (d < NDIS) { x = x0; off = off0; csr = csr0; ou = o0; }
    else { d -= NDIS; x = x1; off = off1; csr = csr1; ou = o1; }
    const int tid = threadIdx.x;     // 128
    const int slot = tid >> 5;       // 0..3: which edge of the group
    const int lr = tid & 31;         // lane within row (16B each)
    int s = off[d], e = off[d + 1];
    float a[8] = {};
    int i = s;
    auto ACC = [&](uint4 v) {
        a[0] += bf2f(v.x & 0xffffu); a[1] += bf2f(v.x >> 16);
        a[2] += bf2f(v.y & 0xffffu); a[3] += bf2f(v.y >> 16);
        a[4] += bf2f(v.z & 0xffffu); a[5] += bf2f(v.z >> 16);
        a[6] += bf2f(v.w & 0xffffu); a[7] += bf2f(v.w >> 16);
    };
    for (; i + 8 <= e; i += 8) {
        int i0 = csr[i + slot], i1 = csr[i + 4 + slot];
        uint4 v0 = *(const uint4*)&x[(size_t)i0 * 128 + lr * 4];
        uint4 v1 = *(const uint4*)&x[(size_t)i1 * 128 + lr * 4];
        ACC(v0); ACC(v1);
    }
    for (; i + 4 <= e; i += 4) {
        int i0 = csr[i + slot];
        uint4 v0 = *(const uint4*)&x[(size_t)i0 * 128 + lr * 4];
        ACC(v0);
    }
    int rem = e - i;
    if (slot < rem) {
        int i0 = csr[i + slot];
        uint4 v0 = *(const uint4*)&x[(size_t)i0 * 128 + lr * 4];
        ACC(v0);
    }
#pragma unroll
    for (int j = 0; j < 8; ++j) a[j] += __shfl_xor(a[j], 32);
    if (tid >= 64 && tid < 96) {
#pragma unroll
        for (int j = 0; j < 8; ++j) red[lr][j] = a[j];
    }
    __syncthreads();
    if (tid < 32) {
        float inv = 1.f / fmaxf((float)(e - s), 1.f);
        uint4 o;
        float r0, r1;
        r0 = (a[0] + red[lr][0]) * inv; r1 = (a[1] + red[lr][1]) * inv;
        o.x = (uint_t)f2bf(r0) | ((uint_t)f2bf(r1) << 16);
        r0 = (a[2] + red[lr][2]) * inv; r1 = (a[3] + red[lr][3]) * inv;
        o.y = (uint_t)f2bf(r0) | ((uint_t)f2bf(r1) << 16);
        r0 = (a[4] + red[lr][4]) * inv; r1 = (a[5] + red[lr][5]) * inv;
        o.z = (uint_t)f2bf(r0) | ((uint_t)f2bf(r1) << 16);
        r0 = (a[6] + red[lr][6]) * inv; r1 = (a[7] + red[lr][7]) * inv;
        o.w = (uint_t)f2bf(r0) | ((uint_t)f2bf(r1) << 16);
        *(uint4*)&ou[(size_t)d * 128 + lr * 4] = o;
    }
}

// ---------------- A-share alternating-B MFMA GEMM (layer path)
// RACE-FREE 1-barrier schedule (round 12, verified)
struct GJob {
    const ushort_t* A[2];
    const ushort_t* Bh[2];
    const ushort_t* Bl[2];
    int astride, wstride;
    const float* bias;
    int M, N, relu, nTiles;
    ushort_t* C;
};

template<int NA, int SPP>
__global__ __launch_bounds__(256, 4) void k_mgemm(GJob j0, GJob j1, int blocks0)
{
    __shared__ __align__(16) ushort_t Ab[2][4096];   // [slot][128 x 32]
    __shared__ __align__(16) ushort_t Bb[3][4096];   // [slot][128 x 32]

    const int tid = threadIdx.x;
    const int lane = tid & 63;
    const int wv = tid >> 6;

    const int bid = blockIdx.x;
    const bool second = (bid >= blocks0);
    const GJob j = second ? j1 : j0;
    const int nblk = second ? ((int)gridDim.x - blocks0) : blocks0;
    const int tloc = second ? (bid - blocks0) : bid;
    const int t = xcd_swz(tloc, nblk);
    const int bm = ((j.nTiles == 2) ? (t >> 1) : t) * 128;
    const int bn = ((j.nTiles == 2) ? (t & 1) : 0) * 128;

    const int q = tid >> 2;                                   // 0..63
    const int skz = (((tid & 3) ^ ((tid >> 3) & 3)) << 3);    // chunk-XOR swizzle

    int tr0 = bm + q;       if (tr0 > j.M - 1) tr0 = j.M - 1;
    int tr1 = bm + 64 + q;  if (tr1 > j.M - 1) tr1 = j.M - 1;
    const size_t aoff0 = (size_t)tr0 * j.astride + skz;
    const size_t aoff1 = (size_t)tr1 * j.astride + skz;
    const size_t boff = (size_t)(bn + q) * j.wstride + skz;
    const size_t ws64 = (size_t)64 * j.wstride;

    auto STAGE_A = [&](int u, int slot) {
        const int a = u / SPP, ks = u % SPP;
        const ushort_t* Ap = j.A[a] + (size_t)ks * 32;
        gl_lds16(Ap + aoff0, &Ab[slot][wv * 512]);
        gl_lds16(Ap + aoff1, &Ab[slot][2048 + wv * 512]);
    };
    auto STAGE_B = [&](int s2, int slot) {
        const int u = s2 >> 1, a = u / SPP, ks = u % SPP, h = s2 & 1;
        const ushort_t* Bp = (h ? j.Bl[a] : j.Bh[a]) + boff + (size_t)ks * 32;
        gl_lds16(Bp,        &Bb[slot][wv * 512]);
        gl_lds16(Bp + ws64, &Bb[slot][2048 + wv * 512]);
    };

    f32x4 acc[4][4] = {};
    s16x8 a_frag[4];
    const int arow = lane & 15;
    const int k8s = ((lane >> 4) * 8) ^ (((arow >> 1) & 3) << 3);
    const int wrA = (wv >> 1) * 64;
    const int wrB = (wv & 1) * 64;

    constexpr int NS = NA * SPP * 2;
    STAGE_A(0, 0); STAGE_B(0, 0);     // 4 loads (step 0)
    STAGE_B(1, 1);                    // 2 loads (step 1)
    asm volatile("s_waitcnt vmcnt(2)" ::: "memory");
    __builtin_amdgcn_sched_barrier(0);
    __builtin_amdgcn_s_barrier();

#pragma unroll
    for (int s = 0; s < NS; ++s) {
        const int bslot = s % 3;
        if (s + 2 < NS) {
            if (((s + 2) & 1) == 0) STAGE_A((s + 2) >> 1, ((s + 2) >> 1) & 1);
            STAGE_B(s + 2, (s + 2) % 3);
        }
        if ((s & 1) == 0) {
            const int aslot = (s >> 1) & 1;
#pragma unroll
            for (int m = 0; m < 4; ++m)
                a_frag[m] = *(const s16x8*)&Ab[aslot][(wrA + m * 16 + arow) * 32 + k8s];
        }
        __builtin_amdgcn_s_setprio(1);
#pragma unroll
        for (int n = 0; n < 4; ++n) {
            s16x8 b = *(const s16x8*)&Bb[bslot][(wrB + n * 16 + arow) * 32 + k8s];
#pragma unroll
            for (int m = 0; m < 4; ++m)
                acc[m][n] = __builtin_amdgcn_mfma_f32_16x16x32_bf16(a_frag[m], b, acc[m][n], 0, 0, 0);
        }
        __builtin_amdgcn_s_setprio(0);
        if (s + 2 < NS) {
            if (((s + 2) & 1) == 0) asm volatile("s_waitcnt vmcnt(4)" ::: "memory");
            else                    asm volatile("s_waitcnt vmcnt(2)" ::: "memory");
        } else {
            asm volatile("s_waitcnt vmcnt(0)" ::: "memory");
        }
        __builtin_amdgcn_sched_barrier(0);
        __builtin_amdgcn_s_barrier();
    }

    const int colC = lane & 15;
    const int rb = (lane >> 4) * 4;
#pragma unroll
    for (int m = 0; m < 4; ++m) {
#pragma unroll
        for (int jj = 0; jj < 4; ++jj) {
            const int r = bm + wrA + m * 16 + rb + jj;
            if (r < j.M) {
#pragma unroll
                for (int n = 0; n < 4; ++n) {
                    const int c = bn + wrB + n * 16 + colC;
                    if (c < j.N) {
                        float v = acc[m][n][jj] + j.bias[c];
                        if (j.relu) v = fmaxf(v, 0.f);
                        j.C[(size_t)r * j.N + c] = f2bf(v);
                    }
                }
            }
        }
    }
}

// ---------------- fully fused classifier (round-12/14 verified version)
__global__ __launch_bounds__(256, 2) void k_cls(
    const ushort_t* __restrict__ xg, const ushort_t* __restrict__ xd,
    const int* __restrict__ elbl,
    const ushort_t* __restrict__ w1h, const ushort_t* __restrict__ w1l,
    const ushort_t* __restrict__ w2h, const ushort_t* __restrict__ w2l,
    const ushort_t* __restrict__ w3h, const ushort_t* __restrict__ w3l,
    const float* __restrict__ b1, const float* __restrict__ b2,
    const float* __restrict__ b3, const float* __restrict__ w4,
    const float* __restrict__ b4, float* __restrict__ out, int M)
{
    // staging: A = [0,4096) (2 slots x 2048), B = [4096,28672) (3 slots x 8192)
    // post-fc1 reuse: e1 = [0,16384), e2 = [16384,24576), part = [24576,25088)
    __shared__ __align__(16) ushort_t sm[28672];

    const int tid = threadIdx.x;
    const int lane = tid & 63;
    const int wv = tid >> 6;
    const int bm = blockIdx.x * 64;
    const int arow = lane & 15;
    const int kq = lane >> 4;          // 0..3
    const int rb = kq * 4;
    const int colC = arow;

    const int q = tid >> 2;                                   // 0..63
    const int skz = (((tid & 3) ^ ((tid >> 3) & 3)) << 3);    // chunk-XOR swizzle

    int r0 = bm + q; if (r0 > M - 1) r0 = M - 1;
    const size_t aoff[2] = { (size_t)elbl[r0] * 256 + skz,
                             (size_t)elbl[NEL + r0] * 256 + skz };
    const ushort_t* xsrc[2] = { xg, xd };
    const size_t bq = (size_t)q * 512 + skz;

    auto STAGE_A = [&](int u, int slot) {           // 1 load; u: pass u>>3, k-chunk u&7
        const int p = u >> 3, ks = u & 7;
        gl_lds16(xsrc[p] + aoff[p] + ks * 32, &sm[slot * 2048 + wv * 512]);
    };
    auto STAGE_B = [&](int s2, int slot) {          // 4 loads: 256-row B tile
        const int u = s2 >> 1, p = u >> 3, ks = u & 7, h = s2 & 1;
        const ushort_t* W = (h ? w1l : w1h) + (size_t)p * 256 + (size_t)ks * 32 + bq;
        ushort_t* db = &sm[4096 + slot * 8192 + wv * 512];
#pragma unroll
        for (int i = 0; i < 4; ++i)
            gl_lds16(W + (size_t)i * 64 * 512, db + i * 2048);
    };

    f32x4 acc1[4][4] = {};
    s16x8 af[4];
    const int k8s = (kq * 8) ^ (((arow >> 1) & 3) << 3);

    STAGE_A(0, 0); STAGE_B(0, 0);     // 5 loads (step 0)
    STAGE_B(1, 1);                    // 4 loads (step 1)
    asm volatile("s_waitcnt vmcnt(4)" ::: "memory");   // drain step 0
    __builtin_amdgcn_sched_barrier(0);
    __builtin_amdgcn_s_barrier();

#pragma unroll
    for (int s = 0; s < 32; ++s) {
        const int bslot = s % 3;
        if (s + 2 < 32) {
            if (((s + 2) & 1) == 0) STAGE_A((s + 2) >> 1, ((s + 2) >> 1) & 1);
            STAGE_B(s + 2, (s + 2) % 3);
        }
        if ((s & 1) == 0) {
            const int aslot = (s >> 1) & 1;
#pragma unroll
            for (int m = 0; m < 4; ++m)
                af[m] = *(const s16x8*)&sm[aslot * 2048 + (m * 16 + arow) * 32 + k8s];
        }
        __builtin_amdgcn_s_setprio(1);
#pragma unroll
        for (int n = 0; n < 4; ++n) {
            s16x8 b = *(const s16x8*)&sm[4096 + bslot * 8192 + (wv * 64 + n * 16 + arow) * 32 + k8s];
#pragma unroll
            for (int m = 0; m < 4; ++m)
                acc1[m][n] = __builtin_amdgcn_mfma_f32_16x16x32_bf16(af[m], b, acc1[m][n], 0, 0, 0);
        }
        __builtin_amdgcn_s_setprio(0);
        if (s + 2 < 32) {
            if (((s + 2) & 1) == 0) asm volatile("s_waitcnt vmcnt(5)" ::: "memory");
            else                    asm volatile("s_waitcnt vmcnt(4)" ::: "memory");
        } else {
            asm volatile("s_waitcnt vmcnt(0)" ::: "memory");
        }
        __builtin_amdgcn_sched_barrier(0);
        __builtin_amdgcn_s_barrier();
    }

    // e1 -> LDS [64][256] bf16, chunk-XOR swizzled (chunk ^= row&7)
#pragma unroll
    for (int m = 0; m < 4; ++m)
#pragma unroll
        for (int n = 0; n < 4; ++n)
#pragma unroll
            for (int jj = 0; jj < 4; ++jj) {
                int row = m * 16 + rb + jj;
                int col = wv * 64 + n * 16 + colC;
                float v = acc1[m][n][jj] + b1[col];
                v = fmaxf(v, 0.f);
                int c = col >> 3;
                sm[row * 256 + (((c ^ (row & 7)) << 3) | (col & 7))] = f2bf(v);
            }
    __syncthreads();

    // ---- phase 2: fc2 (K=256, N=128). A from e1 LDS; B direct global ----
    f32x4 acc2[4][2] = {};
#pragma unroll
    for (int k = 0; k < 8; ++k) {
        s16x8 a2[4];
#pragma unroll
        for (int m = 0; m < 4; ++m) {
            int row = m * 16 + arow;
            int c = k * 4 + kq;
            a2[m] = *(const s16x8*)&sm[row * 256 + ((c ^ (row & 7)) << 3)];
        }
#pragma unroll
        for (int nt = 0; nt < 2; ++nt) {
            size_t bo = (size_t)(wv * 32 + nt * 16 + arow) * 256 + k * 32 + kq * 8;
            s16x8 bh = *(const s16x8*)(w2h + bo);
            s16x8 bl = *(const s16x8*)(w2l + bo);
#pragma unroll
            for (int m = 0; m < 4; ++m) {
                acc2[m][nt] = __builtin_amdgcn_mfma_f32_16x16x32_bf16(a2[m], bh, acc2[m][nt], 0, 0, 0);
                acc2[m][nt] = __builtin_amdgcn_mfma_f32_16x16x32_bf16(a2[m], bl, acc2[m][nt], 0, 0, 0);
            }
        }
    }
    // e2 -> LDS [64][128] bf16 swizzled (disjoint region from e1)
#pragma unroll
    for (int m = 0; m < 4; ++m)
#pragma unroll
        for (int nt = 0; nt < 2; ++nt)
#pragma unroll
            for (int jj = 0; jj < 4; ++jj) {
                int row = m * 16 + rb + jj;
                int col = wv * 32 + nt * 16 + colC;
                float v = acc2[m][nt][jj] + b2[col];
                v = fmaxf(v, 0.f);
                int c = col >> 3;
                sm[16384 + row * 128 + (((c ^ (row & 7)) << 3) | (col & 7))] = f2bf(v);
            }
    __syncthreads();

    // ---- phase 3: fc3 (K=128, N=64). Wave wv owns cols wv*16..+15 ----
    f32x4 acc3[4] = {};
#pragma unroll
    for (int k = 0; k < 4; ++k) {
        s16x8 a3[4];
#pragma unroll
        for (int m = 0; m < 4; ++m) {
            int row = m * 16 + arow;
            int c = k * 4 + kq;
            a3[m] = *(const s16x8*)&sm[16384 + row * 128 + ((c ^ (row & 7)) << 3)];
        }
        size_t bo = (size_t)(wv * 16 + arow) * 128 + k * 32 + kq * 8;
        s16x8 bh = *(const s16x8*)(w3h + bo);
        s16x8 bl = *(const s16x8*)(w3l + bo);
#pragma unroll
        for (int m = 0; m < 4; ++m) {
            acc3[m] = __builtin_amdgcn_mfma_f32_16x16x32_bf16(a3[m], bh, acc3[m], 0, 0, 0);
            acc3[m] = __builtin_amdgcn_mfma_f32_16x16x32_bf16(a3[m], bl, acc3[m], 0, 0, 0);
        }
    }

    // ---- phase 4: fc4 dot. 16-lane shfl reduce, then cross-wave LDS sum ----
    float* part = (float*)&sm[24576];   // [4][64]
#pragma unroll
    for (int m = 0; m < 4; ++m)
#pragma unroll
        for (int jj = 0; jj < 4; ++jj) {
            int row = m * 16 + rb + jj;
            int col = wv * 16 + colC;
            float e = acc3[m][jj] + b3[col];
            e = fmaxf(e, 0.f);
            float v = e * w4[col];
#pragma unroll
            for (int o = 1; o < 16; o <<= 1) v += __shfl_xor(v, o);
            if (colC == 0) part[wv * 64 + row] = v;
        }
    __syncthreads();
    if (tid < 64) {
        int rr = bm + tid;
        if (rr < M)
            out[rr] = part[tid] + part[64 + tid] + part[128 + tid] + part[192 + tid] + b4[0];
    }
}

extern "C" void kernel_launch(void* const* d_in, const int* in_sizes, int n_in,
                              void* d_out, int out_size, void* d_ws, size_t ws_size,
                              hipStream_t stream)
{
    const int*   drug_id   = (const int*)d_in[0];
    const float* disease_x = (const float*)d_in[1];
    const int*   dis_id    = (const int*)d_in[2];
    const int*   e_mt      = (const int*)d_in[3];
    const int*   e_rev     = (const int*)d_in[4];
    const int*   e_lbl     = (const int*)d_in[5];
    const float* drug_emb  = (const float*)d_in[6];
    const float* dis_emb   = (const float*)d_in[7];
    const float* lin_w     = (const float*)d_in[8];
    const float* lin_b     = (const float*)d_in[9];
    const float* Wl_mt     = (const float*)d_in[10];
    const float* bl_mt     = (const float*)d_in[11];
    const float* Wr_mt     = (const float*)d_in[12];
    const float* Wl_rev    = (const float*)d_in[13];
    const float* bl_rev    = (const float*)d_in[14];
    const float* Wr_rev    = (const float*)d_in[15];
    const float* fc1_w = (const float*)d_in[16]; const float* fc1_b = (const float*)d_in[17];
    const float* fc2_w = (const float*)d_in[18]; const float* fc2_b = (const float*)d_in[19];
    const float* fc3_w = (const float*)d_in[20]; const float* fc3_b = (const float*)d_in[21];
    const float* fc4_w = (const float*)d_in[22]; const float* fc4_b = (const float*)d_in[23];
    float* out = (float*)d_out;

    // ---- workspace layout (~75 MB) ----
    char* base = (char*)d_ws;
    size_t o = 0;
    auto alloc = [&](size_t bytes) { char* r = base + o; o += (bytes + 255) & ~(size_t)255; return r; };
    const size_t XB = (size_t)20000 * 256 * 2;   // one bf16 activation plane

    ushort_t* x_dis   = (ushort_t*)alloc(XB);
    ushort_t* x_drug  = (ushort_t*)alloc(XB);
    ushort_t* y_dis   = (ushort_t*)alloc(XB);
    ushort_t* y_drug  = (ushort_t*)alloc(XB);
    ushort_t* agg_dis = (ushort_t*)alloc(XB);
    ushort_t* agg_drug= (ushort_t*)alloc(XB);
    const size_t WB = (size_t)4 * 256 * 256 * 2;
    ushort_t* wlmt_h  = (ushort_t*)alloc(WB); ushort_t* wlmt_l  = (ushort_t*)alloc(WB);
    ushort_t* wrmt_h  = (ushort_t*)alloc(WB); ushort_t* wrmt_l  = (ushort_t*)alloc(WB);
    ushort_t* wlrev_h = (ushort_t*)alloc(WB); ushort_t* wlrev_l = (ushort_t*)alloc(WB);
    ushort_t* wrrev_h = (ushort_t*)alloc(WB); ushort_t* wrrev_l = (ushort_t*)alloc(WB);
    ushort_t* fc1t_h  = (ushort_t*)alloc(512 * 256 * 2); ushort_t* fc1t_l = (ushort_t*)alloc(512 * 256 * 2);
    ushort_t* fc2t_h  = (ushort_t*)alloc(256 * 128 * 2); ushort_t* fc2t_l = (ushort_t*)alloc(256 * 128 * 2);
    ushort_t* fc3t_h  = (ushort_t*)alloc(128 * 64 * 2);  ushort_t* fc3t_l = (ushort_t*)alloc(128 * 64 * 2);
    int* cnts     = (int*)alloc(80000 * 4);
    int* cnt_dis  = cnts;
    int* cnt_drug = cnts + 20000;
    int* cur_dis  = cnts + 40000;
    int* cur_drug = cnts + 60000;
    int* off_dis  = (int*)alloc(20004 * 4);
    int* off_drug = (int*)alloc(20004 * 4);
    int* csr_mt   = (int*)alloc(400000 * 4);
    int* csr_rev  = (int*)alloc(400000 * 4);

    hipMemsetAsync(cnts, 0, 80000 * sizeof(int), stream);

    TP tp;
    tp.src[0] = Wl_mt;  tp.th[0] = wlmt_h;  tp.tl[0] = wlmt_l;
    tp.src[1] = Wr_mt;  tp.th[1] = wrmt_h;  tp.tl[1] = wrmt_l;
    tp.src[2] = Wl_rev; tp.th[2] = wlrev_h; tp.tl[2] = wlrev_l;
    tp.src[3] = Wr_rev; tp.th[3] = wrrev_h; tp.tl[3] = wrrev_l;
    tp.src[4] = fc1_w;  tp.th[4] = fc1t_h;  tp.tl[4] = fc1t_l;
    tp.src[5] = fc2_w;  tp.th[5] = fc2t_h;  tp.tl[5] = fc2t_l;
    tp.src[6] = fc3_w;  tp.th[6] = fc3t_h;  tp.tl[6] = fc3t_l;

    // mega prep: trans (298) | init (20000) | count (2*NBE)
    k_prep<<<298 + 20000 + 2 * NBE, 256, 0, stream>>>(
        tp, drug_id, drug_emb, disease_x, lin_w, lin_b, dis_id, dis_emb,
        x_drug, x_dis, e_mt + NE, e_rev + NE, cnt_dis, cnt_drug);
    k_scan2<<<2, 1024, 0, stream>>>(cnt_dis, off_dis, cnt_drug, off_drug, 20000);
    k_fill2<<<2 * NBE, 256, 0, stream>>>(e_mt, e_rev, off_dis, off_drug,
                                         cur_dis, cur_drug, csr_mt, csr_rev);

    ushort_t *xd = x_dis, *xg = x_drug;
    ushort_t *td = y_dis, *tg = y_drug;
    const int mT = (20000 + 127) / 128;     // 157
    for (int l = 0; l < NLAYERS; ++l) {
        int relu = (l < NLAYERS - 1) ? 1 : 0;
        size_t wo = (size_t)l * 65536;
        k_agg2<<<NDIS + NDRUG, 128, 0, stream>>>(
            (const uint_t*)xg, off_dis, csr_mt, (uint_t*)agg_dis,
            (const uint_t*)xd, off_drug, csr_rev, (uint_t*)agg_drug);
        GJob jd = { { agg_dis, xd }, { wlmt_h + wo, wrmt_h + wo }, { wlmt_l + wo, wrmt_l + wo },
                    256, 256, bl_mt + l * HID, NDIS, 256, relu, 2, td };
        GJob jg = { { agg_drug, xg }, { wlrev_h + wo, wrrev_h + wo }, { wlrev_l + wo, wrrev_l + wo },
                    256, 256, bl_rev + l * HID, NDRUG, 256, relu, 2, tg };
        k_mgemm<2, 8><<<mT * 4, 256, 0, stream>>>(jd, jg, mT * 2);
        ushort_t* t;
        t = xd; xd = td; td = t;
        t = xg; xg = tg; tg = t;
    }

    // fully fused classifier: one dispatch
    k_cls<<<(NEL + 63) / 64, 256, 0, stream>>>(
        xg, xd, e_lbl, fc1t_h, fc1t_l, fc2t_h, fc2t_l, fc3t_h, fc3t_l,
        fc1_b, fc2_b, fc3_b, fc4_w, fc4_b, out, NEL);
}